// Round 2
// baseline (1250.878 us; speedup 1.0000x reference)
//
#include <hip/hip_runtime.h>

#define N_NODES 262144
#define NSEG    1024
#define NHK     256     // NUM_HEADS * HIDDEN
#define DIN     512
#define KSTEPS  16      // DIN / 32

typedef __attribute__((ext_vector_type(8))) short          bf16x8;
typedef __attribute__((ext_vector_type(8))) unsigned short u16x8;
typedef __attribute__((ext_vector_type(4))) float          f32x4;

__device__ __forceinline__ unsigned short f2bf(float f){
  unsigned u = __float_as_uint(f);
  u += 0x7FFFu + ((u >> 16) & 1u);
  return (unsigned short)(u >> 16);
}

__device__ __forceinline__ float tanh_fast(float v){
  float z = fminf(fmaxf(v, -15.f), 15.f);
  float e = __expf(2.f * z);
  return (e - 1.f) / (e + 1.f);
}

__device__ __forceinline__ int lower_bound_i(const int* __restrict__ b, int n, int v){
  int lo = 0, hi = n;
  while (lo < hi){ int m = (lo + hi) >> 1; if (b[m] < v) lo = m + 1; else hi = m; }
  return lo;
}

// ---- prep: Wh [256][512] f32 -> wbt [16 ksteps][256 hk][32 d] bf16 ----
__global__ void k_prep_w(const float* __restrict__ wh, unsigned short* __restrict__ wbt){
  int g = blockIdx.x * 256 + threadIdx.x;           // 131072 total
  int ks = g >> 13; int rem = g & 8191; int hk = rem >> 5; int j = rem & 31;
  wbt[g] = f2bf(wh[hk * DIN + ks * 32 + j]);
}

// ---- prep: Wc [512][2048] f32 -> wct [2048][512] f32 (wct[j][o] = Wc[o][j]) ----
__global__ void k_prep_wc(const float* __restrict__ wc, float* __restrict__ wct){
  int g = blockIdx.x * 256 + threadIdx.x;           // 1048576 total
  int j = g >> 9; int o = g & 511;
  wct[g] = wc[o * 2048 + j];
}

// ---- phase 1: scores[n][h] = sum_k tanh(logit[n][hk]+bh)*ctx[hk] via bf16 MFMA ----
__global__ __launch_bounds__(256)
void k_scores(const float* __restrict__ x, const unsigned short* __restrict__ wbt,
              const float* __restrict__ bh, const float* __restrict__ ctx,
              float* __restrict__ scores){
  __shared__ __align__(16) unsigned short aT[64 * 40];   // 64 nodes x 32 k, pad to 40
  __shared__ __align__(16) unsigned short bT[256 * 40];  // 256 hk x 32 k, pad to 40
  __shared__ float ctxs[256];
  __shared__ float bhs[256];
  const int t = threadIdx.x;
  const int w = t >> 6, l = t & 63;
  const int nb = blockIdx.x * 64;
  ctxs[t] = ctx[t];
  bhs[t]  = bh[t];

  f32x4 acc[16];
#pragma unroll
  for (int i = 0; i < 16; ++i) acc[i] = (f32x4){0.f, 0.f, 0.f, 0.f};

  const int arow = t >> 2, apart = t & 3;
  for (int ks = 0; ks < KSTEPS; ++ks){
    // A stage: x[nb..nb+63][ks*32..+31] f32 -> bf16 LDS
    const float* xp = x + ((size_t)(nb + arow) * DIN + ks * 32 + apart * 8);
    f32x4 v0 = *(const f32x4*)xp;
    f32x4 v1 = *(const f32x4*)(xp + 4);
    u16x8 av;
    av[0]=f2bf(v0[0]); av[1]=f2bf(v0[1]); av[2]=f2bf(v0[2]); av[3]=f2bf(v0[3]);
    av[4]=f2bf(v1[0]); av[5]=f2bf(v1[1]); av[6]=f2bf(v1[2]); av[7]=f2bf(v1[3]);
    *(u16x8*)&aT[arow * 40 + apart * 8] = av;
    // B stage: wbt k-tile (contiguous 16KB) -> LDS padded
    const unsigned short* wp = wbt + ks * 8192;
#pragma unroll
    for (int i = 0; i < 4; ++i){
      int c = i * 256 + t;                 // 16B chunk id
      int row = c >> 2, part = c & 3;
      u16x8 bv = *(const u16x8*)(wp + c * 8);
      *(u16x8*)&bT[row * 40 + part * 8] = bv;
    }
    __syncthreads();
    // compute: wave w owns node rows w*16..w*16+15
    bf16x8 af = *(bf16x8*)&aT[(w * 16 + (l & 15)) * 40 + (l >> 4) * 8];
#pragma unroll
    for (int ct = 0; ct < 16; ++ct){
      bf16x8 bf = *(bf16x8*)&bT[(ct * 16 + (l & 15)) * 40 + (l >> 4) * 8];
      acc[ct] = __builtin_amdgcn_mfma_f32_16x16x32_bf16(af, bf, acc[ct], 0, 0, 0);
    }
    __syncthreads();
  }

  // epilogue: logits -> tanh -> *ctx -> reduce over k
  float s[4][4];   // [r][h]
#pragma unroll
  for (int r = 0; r < 4; ++r)
#pragma unroll
    for (int h = 0; h < 4; ++h) s[r][h] = 0.f;

#pragma unroll
  for (int h = 0; h < 4; ++h){
#pragma unroll
    for (int q = 0; q < 4; ++q){
      int ct = h * 4 + q;
      int hk = ct * 16 + (l & 15);
      float cx = ctxs[hk], bb = bhs[hk];
#pragma unroll
      for (int r = 0; r < 4; ++r){
        float lg = acc[ct][r] + bb;
        s[r][h] += tanh_fast(lg) * cx;
      }
    }
  }
  // reduce across the 16 lanes of each l>>4 group
#pragma unroll
  for (int off = 1; off < 16; off <<= 1){
#pragma unroll
    for (int r = 0; r < 4; ++r)
#pragma unroll
      for (int h = 0; h < 4; ++h)
        s[r][h] += __shfl_xor(s[r][h], off);
  }
  if ((l & 15) < 4){
    int h = l & 15;
#pragma unroll
    for (int r = 0; r < 4; ++r){
      int node = nb + w * 16 + (l >> 4) * 4 + r;
      scores[node * 4 + h] = s[r][h];
    }
  }
}

// ---- phase 2: per-segment max and sum(exp) ----
__global__ __launch_bounds__(256)
void k_stats(const float* __restrict__ scores, const int* __restrict__ batch,
             float* __restrict__ segmax, float* __restrict__ segsum){
  int s = blockIdx.x, t = threadIdx.x;
  int start = lower_bound_i(batch, N_NODES, s);
  int end   = lower_bound_i(batch, N_NODES, s + 1);
  __shared__ float red[256];
  __shared__ float mxs[4];
  int h = t & 3, i0 = t >> 2;
  float m = -3.4e38f;
  for (int i = start + i0; i < end; i += 64) m = fmaxf(m, scores[i * 4 + h]);
  red[t] = m; __syncthreads();
  if (t < 4){
    float mm = -3.4e38f;
    for (int i = t; i < 256; i += 4) mm = fmaxf(mm, red[i]);
    mxs[t] = mm; segmax[s * 4 + t] = mm;
  }
  __syncthreads();
  float mh = mxs[h];
  float p = 0.f;
  for (int i = start + i0; i < end; i += 64) p += __expf(scores[i * 4 + h] - mh);
  red[t] = p; __syncthreads();
  if (t < 4){
    float ss = 0.f;
    for (int i = t; i < 256; i += 4) ss += red[i];
    segsum[s * 4 + t] = ss;
  }
}

// ---- phase 3: pooled[s][h*512+d] = sum_n w[n][h] * x[n][d] ----
__global__ __launch_bounds__(256)
void k_pool(const float* __restrict__ x, const float* __restrict__ scores,
            const int* __restrict__ batch, const float* __restrict__ segmax,
            const float* __restrict__ segsum, float* __restrict__ pooled){
  int s = blockIdx.x, t = threadIdx.x;
  int start = lower_bound_i(batch, N_NODES, s);
  int end   = lower_bound_i(batch, N_NODES, s + 1);
  __shared__ float mx[4], rs[4];
  __shared__ float wl[64][4];
  if (t < 4){
    mx[t] = segmax[s * 4 + t];
    float ss = segsum[s * 4 + t];
    rs[t] = ss > 0.f ? 1.f / ss : 0.f;
  }
  __syncthreads();
  float2 a0 = {0.f,0.f}, a1 = {0.f,0.f}, a2 = {0.f,0.f}, a3 = {0.f,0.f};
  const float2* x2 = (const float2*)x;
  for (int nc = start; nc < end; nc += 64){
    int cnt = min(64, end - nc);
    if (t < cnt * 4){
      int i = t >> 2, hh = t & 3;
      wl[i][hh] = __expf(scores[(nc + i) * 4 + hh] - mx[hh]) * rs[hh];
    }
    __syncthreads();
    for (int i = 0; i < cnt; ++i){
      float2 xv = x2[(size_t)(nc + i) * 256 + t];
      float w0 = wl[i][0], w1 = wl[i][1], w2 = wl[i][2], w3 = wl[i][3];
      a0.x += w0 * xv.x; a0.y += w0 * xv.y;
      a1.x += w1 * xv.x; a1.y += w1 * xv.y;
      a2.x += w2 * xv.x; a2.y += w2 * xv.y;
      a3.x += w3 * xv.x; a3.y += w3 * xv.y;
    }
    __syncthreads();
  }
  float2* p2 = (float2*)pooled;
  p2[s * 1024 + 0 * 256 + t] = a0;
  p2[s * 1024 + 1 * 256 + t] = a1;
  p2[s * 1024 + 2 * 256 + t] = a2;
  p2[s * 1024 + 3 * 256 + t] = a3;
}

// ---- phase 4: out[b][o] = sum_j pooled[b][j] * wct[j][o] + bc[o] ----
__global__ __launch_bounds__(256)
void k_out(const float* __restrict__ pooled, const float* __restrict__ wct,
           const float* __restrict__ bc, float* __restrict__ out){
  int rb = blockIdx.x * 8, t = threadIdx.x;
  __shared__ float cl[8][32];
  float2 acc[8];
#pragma unroll
  for (int r = 0; r < 8; ++r) acc[r] = (float2){0.f, 0.f};
  for (int j0 = 0; j0 < 2048; j0 += 32){
    { int r = t >> 5, jj = t & 31; cl[r][jj] = pooled[(rb + r) * 2048 + j0 + jj]; }
    __syncthreads();
#pragma unroll 8
    for (int jj = 0; jj < 32; ++jj){
      float2 wv = *(const float2*)&wct[(j0 + jj) * 512 + 2 * t];
#pragma unroll
      for (int r = 0; r < 8; ++r){
        float c = cl[r][jj];
        acc[r].x += c * wv.x; acc[r].y += c * wv.y;
      }
    }
    __syncthreads();
  }
  float2 b2 = *(const float2*)&bc[2 * t];
  float2* o2 = (float2*)out;
#pragma unroll
  for (int r = 0; r < 8; ++r){
    float2 v = {acc[r].x + b2.x, acc[r].y + b2.y};
    o2[(rb + r) * 256 + t] = v;
  }
}

extern "C" void kernel_launch(void* const* d_in, const int* in_sizes, int n_in,
                              void* d_out, int out_size, void* d_ws, size_t ws_size,
                              hipStream_t stream){
  const float* x     = (const float*)d_in[0];
  const int*   batch = (const int*)d_in[1];
  const float* Wh    = (const float*)d_in[2];
  const float* bh    = (const float*)d_in[3];
  const float* ctx   = (const float*)d_in[4];
  const float* Wc    = (const float*)d_in[5];
  const float* bc    = (const float*)d_in[6];
  float* out = (float*)d_out;

  char* ws = (char*)d_ws;
  unsigned short* wbt  = (unsigned short*)(ws + 0);          // 262144 B
  float* scores        = (float*)(ws + 262144);              // 4 MB
  float* segmax        = (float*)(ws + 4456448);             // 16 KB
  float* segsum        = (float*)(ws + 4472832);             // 16 KB
  float* pooled        = (float*)(ws + 4489216);             // 8 MB
  float* wct           = (float*)(ws + 12877824);            // 4 MB  (ends 17072128)

  k_prep_w <<<512, 256, 0, stream>>>(Wh, wbt);
  k_prep_wc<<<4096, 256, 0, stream>>>(Wc, wct);
  k_scores <<<N_NODES / 64, 256, 0, stream>>>(x, wbt, bh, ctx, scores);
  k_stats  <<<NSEG, 256, 0, stream>>>(scores, batch, segmax, segsum);
  k_pool   <<<NSEG, 256, 0, stream>>>(x, scores, batch, segmax, segsum, pooled);
  k_out    <<<128, 256, 0, stream>>>(pooled, wct, bc, out);
}

// Round 3
// 943.486 us; speedup vs baseline: 1.3258x; 1.3258x over previous
//
#include <hip/hip_runtime.h>

#define NNODES 262144
#define NSEG   1024
#define DIN    512
#define NB     32                 // nodes per k_main block
#define NBLK   (NNODES / NB)      // 8192

typedef __attribute__((ext_vector_type(8))) short bf16x8;
typedef __attribute__((ext_vector_type(4))) float f32x4;

__device__ __forceinline__ unsigned short f2bf(float f){
  unsigned u = __float_as_uint(f);
  u += 0x7FFFu + ((u >> 16) & 1u);
  return (unsigned short)(u >> 16);
}

__device__ __forceinline__ float tanh_fast(float v){
  float z = fminf(fmaxf(v, -15.f), 15.f);
  float e = __expf(2.f * z);
  return (e - 1.f) / (e + 1.f);
}

__device__ __forceinline__ void atomic_addf(float* p, float v){
  __hip_atomic_fetch_add(p, v, __ATOMIC_RELAXED, __HIP_MEMORY_SCOPE_AGENT);
}

// ---- prep: wbt bf16 [16][256][32], wct = Wc^T [2048][512], zero pooled+zsum ----
__global__ __launch_bounds__(256)
void k_prep(const float* __restrict__ wh, const float* __restrict__ wc,
            unsigned short* __restrict__ wbt, float* __restrict__ wct,
            float4* __restrict__ pooled4, float4* __restrict__ zsum4){
  int g = blockIdx.x * 256 + threadIdx.x;
  if (g < 131072){
    int ks = g >> 13, rem = g & 8191, hk = rem >> 5, kl = rem & 31;
    wbt[g] = f2bf(wh[hk * DIN + ks * 32 + kl]);
  } else if (g < 131072 + 1048576){
    int g2 = g - 131072;
    int j = g2 >> 9, o = g2 & 511;
    wct[g2] = wc[o * 2048 + j];
  } else if (g < 131072 + 1048576 + 524288){
    pooled4[g - 131072 - 1048576] = (float4){0.f, 0.f, 0.f, 0.f};
  } else if (g < 131072 + 1048576 + 524288 + 1024){
    zsum4[g - 131072 - 1048576 - 524288] = (float4){0.f, 0.f, 0.f, 0.f};
  }
}

// ---- fused: scores (bf16 MFMA) -> exp -> segment pool (atomics) ----
__global__ __launch_bounds__(256)
void k_main(const float* __restrict__ x, const unsigned short* __restrict__ wbt,
            const float* __restrict__ bh, const float* __restrict__ ctx,
            const int* __restrict__ batch, float* __restrict__ pooled,
            float* __restrict__ zsum){
  __shared__ __align__(16) unsigned short xs[NB * DIN];   // 32 KB, XOR-swizzled
  __shared__ __align__(16) float wl[NB][4];               // exp(score) per node/head
  __shared__ int bcache[NB];
  const int t = threadIdx.x, w = t >> 6, l = t & 63;
  const int nb = blockIdx.x * NB;

  // ---- stage x tile -> bf16 LDS (swizzle: byte ^= (row&7)<<4) ----
  const float4* xp = (const float4*)(x + (size_t)nb * DIN);
#pragma unroll 4
  for (int i = 0; i < 16; ++i){
    float4 v = xp[i * 256 + t];
    int flat = i * 1024 + t * 4;
    int row = flat >> 9, col = flat & 511;
    unsigned lo = (unsigned)f2bf(v.x) | ((unsigned)f2bf(v.y) << 16);
    unsigned hi = (unsigned)f2bf(v.z) | ((unsigned)f2bf(v.w) << 16);
    int byte = (row << 10) + (col << 1);
    byte ^= (row & 7) << 4;
    *(uint2*)((char*)xs + byte) = make_uint2(lo, hi);
  }
  if (t < NB) bcache[t] = batch[nb + t];

  // per-lane head params: wave w == head w (hk = (w*4+q)*16 + (l&15))
  float bhv[4], cxv[4];
#pragma unroll
  for (int q = 0; q < 4; ++q){
    int hk = (w * 4 + q) * 16 + (l & 15);
    bhv[q] = bh[hk];
    cxv[q] = ctx[hk];
  }

  // B fragment prologue (global->reg, perfectly coalesced 1KB/wave/load)
  bf16x8 Ba[4], Bb[4];
#pragma unroll
  for (int q = 0; q < 4; ++q)
    Ba[q] = *(const bf16x8*)(wbt + ((w * 4 + q) * 16 + (l & 15)) * 32 + (l >> 4) * 8);

  f32x4 acc[2][4];
#pragma unroll
  for (int nt = 0; nt < 2; ++nt)
#pragma unroll
    for (int q = 0; q < 4; ++q) acc[nt][q] = (f32x4){0.f, 0.f, 0.f, 0.f};

  __syncthreads();

  const int fr  = (l & 15);          // frag row within tile
  const int fcb = (l >> 4) * 16;     // frag col byte offset within kstep chunk
#pragma unroll
  for (int ks2 = 0; ks2 < 16; ks2 += 2){
    // prefetch ks2+1
    {
      const unsigned short* wp = wbt + (ks2 + 1) * 8192;
#pragma unroll
      for (int q = 0; q < 4; ++q)
        Bb[q] = *(const bf16x8*)(wp + ((w * 4 + q) * 16 + fr) * 32 + (l >> 4) * 8);
    }
    {
      int b0 = (fr << 10) + (ks2 << 6) + fcb;        b0 ^= (fr & 7) << 4;
      int b1 = ((16 + fr) << 10) + (ks2 << 6) + fcb; b1 ^= (fr & 7) << 4;
      bf16x8 A0 = *(const bf16x8*)((const char*)xs + b0);
      bf16x8 A1 = *(const bf16x8*)((const char*)xs + b1);
#pragma unroll
      for (int q = 0; q < 4; ++q){
        acc[0][q] = __builtin_amdgcn_mfma_f32_16x16x32_bf16(A0, Ba[q], acc[0][q], 0, 0, 0);
        acc[1][q] = __builtin_amdgcn_mfma_f32_16x16x32_bf16(A1, Ba[q], acc[1][q], 0, 0, 0);
      }
    }
    if (ks2 + 2 < 16){
      const unsigned short* wp = wbt + (ks2 + 2) * 8192;
#pragma unroll
      for (int q = 0; q < 4; ++q)
        Ba[q] = *(const bf16x8*)(wp + ((w * 4 + q) * 16 + fr) * 32 + (l >> 4) * 8);
    }
    {
      int b0 = (fr << 10) + ((ks2 + 1) << 6) + fcb;        b0 ^= (fr & 7) << 4;
      int b1 = ((16 + fr) << 10) + ((ks2 + 1) << 6) + fcb; b1 ^= (fr & 7) << 4;
      bf16x8 A0 = *(const bf16x8*)((const char*)xs + b0);
      bf16x8 A1 = *(const bf16x8*)((const char*)xs + b1);
#pragma unroll
      for (int q = 0; q < 4; ++q){
        acc[0][q] = __builtin_amdgcn_mfma_f32_16x16x32_bf16(A0, Bb[q], acc[0][q], 0, 0, 0);
        acc[1][q] = __builtin_amdgcn_mfma_f32_16x16x32_bf16(A1, Bb[q], acc[1][q], 0, 0, 0);
      }
    }
  }

  // ---- epilogue: score[node][head w] = sum_hk tanh(logit+bh)*ctx; w = exp(score) ----
#pragma unroll
  for (int r = 0; r < 4; ++r){
    float s0 = 0.f, s1 = 0.f;
#pragma unroll
    for (int q = 0; q < 4; ++q){
      s0 += tanh_fast(acc[0][q][r] + bhv[q]) * cxv[q];
      s1 += tanh_fast(acc[1][q][r] + bhv[q]) * cxv[q];
    }
#pragma unroll
    for (int off = 1; off < 16; off <<= 1){
      s0 += __shfl_xor(s0, off);
      s1 += __shfl_xor(s1, off);
    }
    if ((l & 15) == 0){
      int node0 = (l >> 4) * 4 + r;
      wl[node0][w]      = __expf(s0);
      wl[16 + node0][w] = __expf(s1);
    }
  }
  __syncthreads();

  // ---- pool phase: thread owns cols 2t,2t+1; accumulate, flush per segment run ----
  float2 a0 = {0.f,0.f}, a1 = {0.f,0.f}, a2 = {0.f,0.f}, a3 = {0.f,0.f};
  int cur = bcache[0], run0 = 0;

#pragma unroll 4
  for (int n = 0; n < NB; ++n){
    int sg = bcache[n];
    if (sg != cur){                    // uniform branch (same n for all threads)
      float* base = pooled + (size_t)cur * 2048 + 2 * t;
      atomic_addf(base + 0,      a0.x); atomic_addf(base + 1,      a0.y);
      atomic_addf(base + 512,    a1.x); atomic_addf(base + 513,    a1.y);
      atomic_addf(base + 1024,   a2.x); atomic_addf(base + 1025,   a2.y);
      atomic_addf(base + 1536,   a3.x); atomic_addf(base + 1537,   a3.y);
      if (t < 4){
        float zs = 0.f;
        for (int m = run0; m < n; ++m) zs += wl[m][t];
        atomic_addf(zsum + cur * 4 + t, zs);
      }
      a0 = a1 = a2 = a3 = (float2){0.f, 0.f};
      cur = sg; run0 = n;
    }
    int byte = (n << 10) + (t << 2);
    byte ^= (n & 7) << 4;
    unsigned xv = *(const unsigned*)((const char*)xs + byte);
    float x0 = __uint_as_float(xv << 16);
    float x1 = __uint_as_float(xv & 0xFFFF0000u);
    float4 wv = *(const float4*)&wl[n][0];
    a0.x += wv.x * x0; a0.y += wv.x * x1;
    a1.x += wv.y * x0; a1.y += wv.y * x1;
    a2.x += wv.z * x0; a2.y += wv.z * x1;
    a3.x += wv.w * x0; a3.y += wv.w * x1;
  }
  {
    float* base = pooled + (size_t)cur * 2048 + 2 * t;
    atomic_addf(base + 0,      a0.x); atomic_addf(base + 1,      a0.y);
    atomic_addf(base + 512,    a1.x); atomic_addf(base + 513,    a1.y);
    atomic_addf(base + 1024,   a2.x); atomic_addf(base + 1025,   a2.y);
    atomic_addf(base + 1536,   a3.x); atomic_addf(base + 1537,   a3.y);
    if (t < 4){
      float zs = 0.f;
      for (int m = run0; m < NB; ++m) zs += wl[m][t];
      atomic_addf(zsum + cur * 4 + t, zs);
    }
  }
}

// ---- out: normalize pooled by Z, GEMM [1024x2048]x[2048x512] + bias ----
__global__ __launch_bounds__(256)
void k_out(const float* __restrict__ pooled, const float* __restrict__ wct,
           const float* __restrict__ zsum, const float* __restrict__ bias,
           float* __restrict__ out){
  __shared__ float ps[32][32];     // pooled tile (normalized)
  __shared__ float wt[32][64];     // wct tile
  __shared__ float rz[32][4];
  const int t = threadIdx.x;
  const int br = blockIdx.x >> 3, bc = blockIdx.x & 7;
  const int r0 = br * 32, c0 = bc * 64;
  if (t < 128){
    int row = t >> 2, h = t & 3;
    float z = zsum[(r0 + row) * 4 + h];
    rz[row][h] = (z > 0.f) ? 1.f / z : 0.f;
  }
  __syncthreads();

  const int w4 = t >> 6, col = t & 63;
  float acc[8];
#pragma unroll
  for (int i = 0; i < 8; ++i) acc[i] = 0.f;

  for (int j0 = 0; j0 < 2048; j0 += 32){
#pragma unroll
    for (int i = 0; i < 4; ++i){            // pooled tile: 1024 elems
      int e = i * 256 + t;
      int row = e >> 5, jj = e & 31;
      int j = j0 + jj;
      ps[row][jj] = pooled[(size_t)(r0 + row) * 2048 + j] * rz[row][j >> 9];
    }
#pragma unroll
    for (int i = 0; i < 8; ++i){            // wct tile: 2048 elems
      int e = i * 256 + t;
      int jr = e >> 6, cc = e & 63;
      wt[jr][cc] = wct[(size_t)(j0 + jr) * 512 + c0 + cc];
    }
    __syncthreads();
#pragma unroll 8
    for (int jj = 0; jj < 32; ++jj){
      float wv = wt[jj][col];
#pragma unroll
      for (int i = 0; i < 8; ++i)
        acc[i] += ps[w4 * 8 + i][jj] * wv;
    }
    __syncthreads();
  }
  float bv = bias[c0 + col];
#pragma unroll
  for (int i = 0; i < 8; ++i)
    out[(size_t)(r0 + w4 * 8 + i) * 512 + c0 + col] = acc[i] + bv;
}

extern "C" void kernel_launch(void* const* d_in, const int* in_sizes, int n_in,
                              void* d_out, int out_size, void* d_ws, size_t ws_size,
                              hipStream_t stream){
  const float* x     = (const float*)d_in[0];
  const int*   batch = (const int*)d_in[1];
  const float* Wh    = (const float*)d_in[2];
  const float* bh    = (const float*)d_in[3];
  const float* ctx   = (const float*)d_in[4];
  const float* Wc    = (const float*)d_in[5];
  const float* bcv   = (const float*)d_in[6];
  float* out = (float*)d_out;

  char* ws = (char*)d_ws;
  unsigned short* wbt = (unsigned short*)(ws + 0);        // 256 KB  [16][256][32] bf16
  float* wct          = (float*)(ws + 262144);            // 4 MB    [2048][512]
  float* pooled       = (float*)(ws + 4456448);           // 8 MB    [1024][4][512]
  float* zsum         = (float*)(ws + 12845056);          // 16 KB   [1024][4]

  k_prep<<<6660, 256, 0, stream>>>(Wh, Wc, wbt, wct, (float4*)pooled, (float4*)zsum);
  k_main<<<NBLK, 256, 0, stream>>>(x, wbt, bh, ctx, batch, pooled, zsum);
  k_out <<<256, 256, 0, stream>>>(pooled, wct, zsum, bcv, out);
}